// Round 8
// baseline (198.109 us; speedup 1.0000x reference)
//
#include <hip/hip_runtime.h>
#include <hip/hip_fp16.h>

#define IN_UNITS 256
#define H1 128
#define H2 64

typedef _Float16 f16x8 __attribute__((ext_vector_type(8)));
typedef float f32x4 __attribute__((ext_vector_type(4)));

union HV { uint4 u; f16x8 v; unsigned short s[8]; };

static __device__ __forceinline__ unsigned short h2bits(_Float16 x) {
    union { _Float16 h; unsigned short u; } c; c.h = x; return c.u;
}

// ---------------- K1: node projections via fp16 MFMA, W1 converted in-kernel --
// block = mtile; wave w: side = w>>1, ch = w&1. One 16-row x 64-col tile per wave.
// W1 frag loads are L2-hot (256 KB shared by all blocks).
__global__ __launch_bounds__(256)
void proj_kernel(
    const float* __restrict__ drug_feat, const float* __restrict__ dis_feat,
    const float* __restrict__ W1, const float* __restrict__ b1,
    unsigned short* __restrict__ drug_h, unsigned short* __restrict__ dis_h,
    int n_rows)
{
    int t = threadIdx.x, lane = t & 63, wave = t >> 6;
    int side = wave >> 1, ch = wave & 1;
    int mtile = blockIdx.x;
    const float* feat = side ? dis_feat : drug_feat;
    unsigned short* outb = side ? dis_h : drug_h;

    int row = mtile * 16 + (lane & 15);
    if (row >= n_rows) row = n_rows - 1;
    int kb = (lane >> 4) * 8;

    // prefetch this lane's full feature strip: 8 ks x 8 floats (HBM, coalesced)
    float4 fx[16];
    #pragma unroll
    for (int i = 0; i < 16; ++i)
        fx[i] = *(const float4*)(feat + (size_t)row * IN_UNITS + (i >> 1) * 32 + kb + (i & 1) * 4);

    // per-lane W1 base: row0 = side*256 + (lane>>4)*8 ; col base = ch*64 + (lane&15)
    const float* w1base = W1 + (size_t)(side * IN_UNITS + (lane >> 4) * 8) * H1
                             + ch * 64 + (lane & 15);

    f32x4 acc[4];
    #pragma unroll
    for (int nt = 0; nt < 4; ++nt) acc[nt] = (f32x4){0.f, 0.f, 0.f, 0.f};

    #pragma unroll
    for (int ks = 0; ks < 8; ++ks) {
        float4 x0 = fx[ks * 2], x1 = fx[ks * 2 + 1];
        f16x8 a;
        a[0] = (_Float16)x0.x; a[1] = (_Float16)x0.y;
        a[2] = (_Float16)x0.z; a[3] = (_Float16)x0.w;
        a[4] = (_Float16)x1.x; a[5] = (_Float16)x1.y;
        a[6] = (_Float16)x1.z; a[7] = (_Float16)x1.w;
        #pragma unroll
        for (int nt = 0; nt < 4; ++nt) {
            HV bb;
            #pragma unroll
            for (int j = 0; j < 8; ++j)
                bb.s[j] = h2bits((_Float16)w1base[(size_t)(ks * 32 + j) * H1 + nt * 16]);
            acc[nt] = __builtin_amdgcn_mfma_f32_16x16x32_f16(a, bb.v, acc[nt], 0, 0, 0);
        }
    }

    #pragma unroll
    for (int nt = 0; nt < 4; ++nt) {
        int col = ch * 64 + nt * 16 + (lane & 15);
        float bb = side ? b1[col] : 0.f;
        #pragma unroll
        for (int r = 0; r < 4; ++r) {
            int rr = mtile * 16 + (lane >> 4) * 4 + r;
            if (rr < n_rows)
                outb[(size_t)rr * H1 + col] = h2bits((_Float16)(acc[nt][r] + bb));
        }
    }
}

// ---------------- K2: per-edge MLP via fp16 MFMA, W2 converted in-kernel ------
// 256 threads = 4 waves; 32 edges/wave; 128 edges/block. High occupancy forced.
__global__ __launch_bounds__(256) __attribute__((amdgpu_waves_per_eu(6, 8)))
void edge_kernel(
    const unsigned short* __restrict__ drug_h, const unsigned short* __restrict__ dis_h,
    const int* __restrict__ src_idx, const int* __restrict__ dst_idx,
    const float* __restrict__ W2, const float* __restrict__ b2,
    const float* __restrict__ W3, const float* __restrict__ b3,
    float* __restrict__ out, int n_edges)
{
    __shared__ uint4 w2s[1024];   // 16 KB fp16 frags: [frag = ks*4+nt][lane]

    int t = threadIdx.x, lane = t & 63;
    int wave = t >> 6;
    int e0 = (blockIdx.x * 4 + wave) * 32;
    int emax = n_edges - 1;

    // 1) edge indices first (HBM stream — start early)
    int i0 = e0 + (lane & 15);      if (i0 > emax) i0 = emax;
    int i1 = e0 + 16 + (lane & 15); if (i1 > emax) i1 = emax;
    int s0 = src_idx[i0], d0 = dst_idx[i0];
    int s1 = src_idx[i1], d1 = dst_idx[i1];

    // 2) convert W2 (fp32, L2-hot) -> fp16 frags in LDS while indices land
    #pragma unroll
    for (int i = 0; i < 4; ++i) {
        int slot = i * 256 + t;          // 0..1023
        int f = slot >> 6, l = slot & 63;
        int ks = f >> 2, nt = f & 3;
        int row0 = ks * 32 + (l >> 4) * 8;
        int col  = nt * 16 + (l & 15);
        HV v;
        #pragma unroll
        for (int j = 0; j < 8; ++j)
            v.s[j] = h2bits((_Float16)W2[(size_t)(row0 + j) * H2 + col]);
        w2s[slot] = v.u;
    }

    // 3) issue all 16 gathers (latency hidden by TLP at 24 waves/CU)
    int kb = (lane >> 4) * 8;
    const uint4* pa0 = (const uint4*)(drug_h + s0 * H1 + kb);
    const uint4* pc0 = (const uint4*)(dis_h  + d0 * H1 + kb);
    const uint4* pa1 = (const uint4*)(drug_h + s1 * H1 + kb);
    const uint4* pc1 = (const uint4*)(dis_h  + d1 * H1 + kb);
    uint4 ga0[4], gc0[4], ga1[4], gc1[4];
    #pragma unroll
    for (int ks = 0; ks < 4; ++ks) {
        ga0[ks] = pa0[ks * 4];
        gc0[ks] = pc0[ks * 4];
        ga1[ks] = pa1[ks * 4];
        gc1[ks] = pc1[ks * 4];
    }

    // 4) epilogue constants (L2-hot)
    float b2v[4], w3v[4];
    #pragma unroll
    for (int nt = 0; nt < 4; ++nt) {
        int col = (lane & 15) + nt * 16;
        b2v[nt] = b2[col];
        w3v[nt] = W3[col];
    }
    float b3v = b3[0];

    __syncthreads();

    f32x4 acc[2][4];
    #pragma unroll
    for (int mt = 0; mt < 2; ++mt)
        #pragma unroll
        for (int nt = 0; nt < 4; ++nt)
            acc[mt][nt] = (f32x4){0.f, 0.f, 0.f, 0.f};

    #pragma unroll
    for (int ks = 0; ks < 4; ++ks) {
        HV a0, c0, a1, c1;
        a0.u = ga0[ks]; c0.u = gc0[ks];
        a1.u = ga1[ks]; c1.u = gc1[ks];
        f16x8 zero = (f16x8)(_Float16)0;
        f16x8 r0v = __builtin_elementwise_max(a0.v + c0.v, zero);  // v_pk_add/max_f16
        f16x8 r1v = __builtin_elementwise_max(a1.v + c1.v, zero);
        #pragma unroll
        for (int nt = 0; nt < 4; ++nt) {
            HV bb; bb.u = w2s[(ks * 4 + nt) * 64 + lane];
            acc[0][nt] = __builtin_amdgcn_mfma_f32_16x16x32_f16(r0v, bb.v, acc[0][nt], 0, 0, 0);
            acc[1][nt] = __builtin_amdgcn_mfma_f32_16x16x32_f16(r1v, bb.v, acc[1][nt], 0, 0, 0);
        }
    }

    // epilogue: out[e] = relu(h2 + b2) . W3 + b3
    // acc[mt][nt][r] = h2[edge = mt*16 + (lane>>4)*4 + r][col = (lane&15) + 16*nt]
    #pragma unroll
    for (int mt = 0; mt < 2; ++mt) {
        float part[4];
        #pragma unroll
        for (int r = 0; r < 4; ++r) {
            float p = 0.f;
            #pragma unroll
            for (int nt = 0; nt < 4; ++nt)
                p += fmaxf(acc[mt][nt][r] + b2v[nt], 0.f) * w3v[nt];
            part[r] = p;
        }
        #pragma unroll
        for (int off = 1; off <= 8; off <<= 1)
            #pragma unroll
            for (int r = 0; r < 4; ++r)
                part[r] += __shfl_xor(part[r], off, 64);
        if ((lane & 15) == 0) {
            #pragma unroll
            for (int r = 0; r < 4; ++r) {
                int e = e0 + mt * 16 + (lane >> 4) * 4 + r;
                if (e < n_edges) out[e] = part[r] + b3v;
            }
        }
    }
}

extern "C" void kernel_launch(void* const* d_in, const int* in_sizes, int n_in,
                              void* d_out, int out_size, void* d_ws, size_t ws_size,
                              hipStream_t stream) {
    const float* drug_feat = (const float*)d_in[0];
    const float* dis_feat  = (const float*)d_in[1];
    const int*   src_idx   = (const int*)d_in[2];
    const int*   dst_idx   = (const int*)d_in[3];
    const float* W1 = (const float*)d_in[4];
    const float* b1 = (const float*)d_in[5];
    const float* W2 = (const float*)d_in[6];
    const float* b2 = (const float*)d_in[7];
    const float* W3 = (const float*)d_in[8];
    const float* b3 = (const float*)d_in[9];
    float* out = (float*)d_out;

    int n_edges = in_sizes[2];
    int n_drug = in_sizes[0] / IN_UNITS;

    // ws layout: [drug_h][dis_h] fp16 tables
    unsigned short* drug_h = (unsigned short*)d_ws;
    unsigned short* dis_h  = drug_h + (size_t)n_drug * H1;

    int mtiles = (n_drug + 15) / 16;                // 625
    proj_kernel<<<mtiles, 256, 0, stream>>>(
        drug_feat, dis_feat, W1, b1, drug_h, dis_h, n_drug);

    int edge_blocks = (n_edges + 127) / 128;        // 7813
    edge_kernel<<<edge_blocks, 256, 0, stream>>>(
        drug_h, dis_h, src_idx, dst_idx, W2, b2, W3, b3, out, n_edges);
}

// Round 9
// 168.076 us; speedup vs baseline: 1.1787x; 1.1787x over previous
//
#include <hip/hip_runtime.h>
#include <hip/hip_fp16.h>

#define IN_UNITS 256
#define H1 128
#define H2 64

typedef _Float16 f16x8 __attribute__((ext_vector_type(8)));
typedef float f32x4 __attribute__((ext_vector_type(4)));

union HV { uint4 u; f16x8 v; unsigned short s[8]; };

static __device__ __forceinline__ unsigned short h2bits(_Float16 x) {
    union { _Float16 h; unsigned short u; } c; c.h = x; return c.u;
}

// ---------------- K1: node projections, K-split across wave pairs ----------
// grid = 2*mtiles (b >= mtiles -> dis side); block 256 = 4 waves.
// wave w: ch = w&1 (64-col half), kh = w>>1 (128-wide K half).
// kh=1 waves drop partials into LDS; kh=0 waves combine + store.
__global__ __launch_bounds__(256)
void proj_kernel(
    const float* __restrict__ drug_feat, const float* __restrict__ dis_feat,
    const float* __restrict__ W1, const float* __restrict__ b1,
    unsigned short* __restrict__ drug_h, unsigned short* __restrict__ dis_h,
    int mtiles, int n_rows)
{
    __shared__ f32x4 lacc[8][64];   // [ch*4+nt][lane], 8 KB

    int t = threadIdx.x, lane = t & 63, wave = t >> 6;
    int ch = wave & 1, kh = wave >> 1;
    int b = blockIdx.x;
    int side = b >= mtiles;
    int mtile = b - side * mtiles;
    const float* feat = side ? dis_feat : drug_feat;
    unsigned short* outb = side ? dis_h : drug_h;

    int row = mtile * 16 + (lane & 15);
    if (row >= n_rows) row = n_rows - 1;
    int kb = (lane >> 4) * 8;

    // this wave's K-half of the feature strip: 4 ks x 8 floats, coalesced-ish
    const float* fp = feat + (size_t)row * IN_UNITS + kh * 128 + kb;
    float4 fx[8];
    #pragma unroll
    for (int i = 0; i < 8; ++i)
        fx[i] = *(const float4*)(fp + (i >> 1) * 32 + (i & 1) * 4);

    // per-lane W1 base for this (side, kh, ch)
    const float* w1base = W1 + (size_t)(side * IN_UNITS + kh * 128 + kb) * H1
                             + ch * 64 + (lane & 15);

    f32x4 acc[4];
    #pragma unroll
    for (int nt = 0; nt < 4; ++nt) acc[nt] = (f32x4){0.f, 0.f, 0.f, 0.f};

    #pragma unroll
    for (int ks = 0; ks < 4; ++ks) {
        float4 x0 = fx[ks * 2], x1 = fx[ks * 2 + 1];
        f16x8 a;
        a[0] = (_Float16)x0.x; a[1] = (_Float16)x0.y;
        a[2] = (_Float16)x0.z; a[3] = (_Float16)x0.w;
        a[4] = (_Float16)x1.x; a[5] = (_Float16)x1.y;
        a[6] = (_Float16)x1.z; a[7] = (_Float16)x1.w;
        #pragma unroll
        for (int nt = 0; nt < 4; ++nt) {
            HV bb;
            #pragma unroll
            for (int j = 0; j < 8; ++j)
                bb.s[j] = h2bits((_Float16)w1base[(size_t)(ks * 32 + j) * H1 + nt * 16]);
            acc[nt] = __builtin_amdgcn_mfma_f32_16x16x32_f16(a, bb.v, acc[nt], 0, 0, 0);
        }
    }

    if (kh == 1) {
        #pragma unroll
        for (int nt = 0; nt < 4; ++nt) lacc[ch * 4 + nt][lane] = acc[nt];
    }
    __syncthreads();
    if (kh == 0) {
        #pragma unroll
        for (int nt = 0; nt < 4; ++nt) {
            f32x4 p = lacc[ch * 4 + nt][lane];
            int col = ch * 64 + nt * 16 + (lane & 15);
            float bbias = side ? b1[col] : 0.f;
            #pragma unroll
            for (int r = 0; r < 4; ++r) {
                int rr = mtile * 16 + (lane >> 4) * 4 + r;
                if (rr < n_rows)
                    outb[(size_t)rr * H1 + col] =
                        h2bits((_Float16)(acc[nt][r] + p[r] + bbias));
            }
        }
    }
}

// ---------------- K2: per-edge MLP, 16 edges/wave, no-spill high TLP --------
// 512 threads = 8 waves; 16 edges/wave; 128 edges/block.
__global__ __launch_bounds__(512) __attribute__((amdgpu_waves_per_eu(6, 8)))
void edge_kernel(
    const unsigned short* __restrict__ drug_h, const unsigned short* __restrict__ dis_h,
    const int* __restrict__ src_idx, const int* __restrict__ dst_idx,
    const float* __restrict__ W2, const float* __restrict__ b2,
    const float* __restrict__ W3, const float* __restrict__ b3,
    float* __restrict__ out, int n_edges)
{
    __shared__ uint4 w2s[1024];   // 16 KB fp16 frags: [frag = ks*4+nt][lane]

    int t = threadIdx.x, lane = t & 63, wave = t >> 6;
    int e0 = blockIdx.x * 128 + wave * 16;
    int emax = n_edges - 1;

    // 1) edge indices
    int i0 = e0 + (lane & 15);
    if (i0 > emax) i0 = emax;
    int s0 = src_idx[i0], d0 = dst_idx[i0];

    // 2) issue this wave's 8 gathers (32 VGPRs live — no spill pressure)
    int kb = (lane >> 4) * 8;
    const uint4* pa = (const uint4*)(drug_h + s0 * H1 + kb);
    const uint4* pc = (const uint4*)(dis_h  + d0 * H1 + kb);
    uint4 ga[4], gc[4];
    #pragma unroll
    for (int ks = 0; ks < 4; ++ks) {
        ga[ks] = pa[ks * 4];
        gc[ks] = pc[ks * 4];
    }

    // 3) convert W2 (fp32, L2-hot) -> fp16 frags in LDS; 2 slots/thread
    #pragma unroll
    for (int i = 0; i < 2; ++i) {
        int slot = i * 512 + t;          // 0..1023
        int f = slot >> 6, l = slot & 63;
        int ks = f >> 2, nt = f & 3;
        int row0 = ks * 32 + (l >> 4) * 8;
        int col  = nt * 16 + (l & 15);
        HV v;
        #pragma unroll
        for (int j = 0; j < 8; ++j)
            v.s[j] = h2bits((_Float16)W2[(size_t)(row0 + j) * H2 + col]);
        w2s[slot] = v.u;
    }
    __syncthreads();

    // 4) MFMA loop: one 16-edge m-tile
    f32x4 acc[4];
    #pragma unroll
    for (int nt = 0; nt < 4; ++nt) acc[nt] = (f32x4){0.f, 0.f, 0.f, 0.f};

    #pragma unroll
    for (int ks = 0; ks < 4; ++ks) {
        HV a, c;
        a.u = ga[ks]; c.u = gc[ks];
        f16x8 zero = (f16x8)(_Float16)0;
        f16x8 rv = __builtin_elementwise_max(a.v + c.v, zero);  // v_pk_add/max_f16
        #pragma unroll
        for (int nt = 0; nt < 4; ++nt) {
            HV bb; bb.u = w2s[(ks * 4 + nt) * 64 + lane];
            acc[nt] = __builtin_amdgcn_mfma_f32_16x16x32_f16(rv, bb.v, acc[nt], 0, 0, 0);
        }
    }

    // 5) epilogue: out[e] = relu(h2 + b2) . W3 + b3
    // acc[nt][r] = h2[edge = (lane>>4)*4 + r][col = (lane&15) + 16*nt]
    float b2v[4], w3v[4];
    #pragma unroll
    for (int nt = 0; nt < 4; ++nt) {
        int col = (lane & 15) + nt * 16;
        b2v[nt] = b2[col];
        w3v[nt] = W3[col];
    }
    float b3v = b3[0];

    float part[4];
    #pragma unroll
    for (int r = 0; r < 4; ++r) {
        float p = 0.f;
        #pragma unroll
        for (int nt = 0; nt < 4; ++nt)
            p += fmaxf(acc[nt][r] + b2v[nt], 0.f) * w3v[nt];
        part[r] = p;
    }
    #pragma unroll
    for (int off = 1; off <= 8; off <<= 1)
        #pragma unroll
        for (int r = 0; r < 4; ++r)
            part[r] += __shfl_xor(part[r], off, 64);
    if ((lane & 15) == 0) {
        #pragma unroll
        for (int r = 0; r < 4; ++r) {
            int e = e0 + (lane >> 4) * 4 + r;
            if (e < n_edges) out[e] = part[r] + b3v;
        }
    }
}

extern "C" void kernel_launch(void* const* d_in, const int* in_sizes, int n_in,
                              void* d_out, int out_size, void* d_ws, size_t ws_size,
                              hipStream_t stream) {
    const float* drug_feat = (const float*)d_in[0];
    const float* dis_feat  = (const float*)d_in[1];
    const int*   src_idx   = (const int*)d_in[2];
    const int*   dst_idx   = (const int*)d_in[3];
    const float* W1 = (const float*)d_in[4];
    const float* b1 = (const float*)d_in[5];
    const float* W2 = (const float*)d_in[6];
    const float* b2 = (const float*)d_in[7];
    const float* W3 = (const float*)d_in[8];
    const float* b3 = (const float*)d_in[9];
    float* out = (float*)d_out;

    int n_edges = in_sizes[2];
    int n_drug = in_sizes[0] / IN_UNITS;

    // ws layout: [drug_h][dis_h] fp16 tables
    unsigned short* drug_h = (unsigned short*)d_ws;
    unsigned short* dis_h  = drug_h + (size_t)n_drug * H1;

    int mtiles = (n_drug + 15) / 16;                // 625
    proj_kernel<<<2 * mtiles, 256, 0, stream>>>(
        drug_feat, dis_feat, W1, b1, drug_h, dis_h, mtiles, n_drug);

    int edge_blocks = (n_edges + 127) / 128;        // 7813
    edge_kernel<<<edge_blocks, 512, 0, stream>>>(
        drug_h, dis_h, src_idx, dst_idx, W2, b2, W3, b3, out, n_edges);
}